// Round 1
// baseline (104.899 us; speedup 1.0000x reference)
//
#include <hip/hip_runtime.h>

// y = (2/pi) * atan(67 * x) / ln(67), elementwise, fp32.
// Memory-bound: 64M elements, 512 MiB total HBM traffic.

#define GAIN 67.0f
// (2.0/pi)/ln(67.0) = 0.6366197723675814 / 4.204692619390966
#define SCALE 0.15140697083726f

__global__ __launch_bounds__(256) void ArcTanDistortion_54365696033609_kernel(
    const float* __restrict__ x, float* __restrict__ y, long long n) {
    long long n4 = n >> 2;  // number of float4 chunks
    const float4* __restrict__ x4 = (const float4*)x;
    float4* __restrict__ y4 = (float4*)y;

    long long idx = (long long)blockIdx.x * blockDim.x + threadIdx.x;
    long long stride = (long long)gridDim.x * blockDim.x;

    for (long long i = idx; i < n4; i += stride) {
        float4 v = x4[i];
        float4 r;
        r.x = atanf(GAIN * v.x) * SCALE;
        r.y = atanf(GAIN * v.y) * SCALE;
        r.z = atanf(GAIN * v.z) * SCALE;
        r.w = atanf(GAIN * v.w) * SCALE;
        y4[i] = r;
    }

    // Scalar tail (n not divisible by 4) — n is 67108864 here so this is
    // a no-op, but keep it correct for any size.
    long long tail_start = n4 << 2;
    for (long long i = tail_start + idx; i < n; i += stride) {
        y[i] = atanf(GAIN * x[i]) * SCALE;
    }
}

extern "C" void kernel_launch(void* const* d_in, const int* in_sizes, int n_in,
                              void* d_out, int out_size, void* d_ws, size_t ws_size,
                              hipStream_t stream) {
    const float* x = (const float*)d_in[0];
    float* y = (float*)d_out;
    long long n = (long long)in_sizes[0];

    const int block = 256;
    // Cap at ~2048 blocks (256 CU x 8 blocks/CU) and grid-stride the rest.
    long long n4 = n >> 2;
    long long want = (n4 + block - 1) / block;
    int grid = (int)(want < 2048 ? (want > 0 ? want : 1) : 2048);

    ArcTanDistortion_54365696033609_kernel<<<grid, block, 0, stream>>>(x, y, n);
}

// Round 2
// 96.384 us; speedup vs baseline: 1.0883x; 1.0883x over previous
//
#include <hip/hip_runtime.h>

// y = (2/pi) * atan(67 * x) / ln(67), elementwise, fp32.
// Memory-bound: 64M elements, 512 MiB HBM traffic -> ~85 us floor @ 6.3 TB/s.
// atanf replaced by fast branch-free approximation:
//   t = 67|x|; u = t>1 ? rcp(t) : t; p = odd-minimax-deg9(u);
//   a = t>1 ? pi/2 - p : p; y = copysign(a*SCALE, x)
// Poly max error ~1e-5 rad -> ~1.5e-6 in output; threshold is 4.75e-3.

typedef float f4 __attribute__((ext_vector_type(4)));

#define GAIN 67.0f
// (2.0/pi)/ln(67.0)
#define SCALE 0.15140697083726f
#define PIO2 1.5707963267948966f

__device__ __forceinline__ float atan_distort(float x) {
    float ax = __builtin_fabsf(x);
    float t = ax * GAIN;
    float r = __builtin_amdgcn_rcpf(t);   // v_rcp_f32, ~1 ulp, plenty accurate
    bool big = t > 1.0f;
    float u = big ? r : t;                // u in [0,1]
    float u2 = u * u;
    // minimax odd deg-9 for atan(u), u in [0,1]
    float p = 0.0208351f;
    p = __builtin_fmaf(p, u2, -0.0851330f);
    p = __builtin_fmaf(p, u2, 0.1801410f);
    p = __builtin_fmaf(p, u2, -0.3302995f);
    p = __builtin_fmaf(p, u2, 0.9998660f);
    p = p * u;
    float a = big ? (PIO2 - p) : p;
    return __builtin_copysignf(a * SCALE, x);
}

__global__ __launch_bounds__(256) void ArcTanDistortion_54365696033609_kernel(
    const float* __restrict__ x, float* __restrict__ y, long long n) {
    long long n4 = n >> 2;
    const f4* __restrict__ x4 = (const f4*)x;
    f4* __restrict__ y4 = (f4*)y;

    long long idx = (long long)blockIdx.x * blockDim.x + threadIdx.x;
    long long stride = (long long)gridDim.x * blockDim.x;

    for (long long i = idx; i < n4; i += stride) {
        f4 v = __builtin_nontemporal_load(&x4[i]);
        f4 o;
        o.x = atan_distort(v.x);
        o.y = atan_distort(v.y);
        o.z = atan_distort(v.z);
        o.w = atan_distort(v.w);
        __builtin_nontemporal_store(o, &y4[i]);
    }

    // Scalar tail (n % 4 != 0) — no-op for n = 64M but kept for generality.
    long long tail_start = n4 << 2;
    for (long long i = tail_start + idx; i < n; i += stride) {
        y[i] = atan_distort(x[i]);
    }
}

extern "C" void kernel_launch(void* const* d_in, const int* in_sizes, int n_in,
                              void* d_out, int out_size, void* d_ws, size_t ws_size,
                              hipStream_t stream) {
    const float* x = (const float*)d_in[0];
    float* y = (float*)d_out;
    long long n = (long long)in_sizes[0];

    const int block = 256;
    long long n4 = n >> 2;
    long long want = (n4 + block - 1) / block;
    int grid = (int)(want < 2048 ? (want > 0 ? want : 1) : 2048);

    ArcTanDistortion_54365696033609_kernel<<<grid, block, 0, stream>>>(x, y, n);
}